// Round 2
// baseline (15891.205 us; speedup 1.0000x reference)
//
#include <hip/hip_runtime.h>

#define BATCH 8192
#define DIN   4096
#define HID   16384
#define KTOP  64

// ---------------- GEMM NT: C[M,N] = act(A[M,K] * B[N,K]^T + bias) ----------------
#define BM 128
#define BN 128
#define BKK 8
#define TM 8
#define TN 8

__global__ __launch_bounds__(256)
void gemm_nt_kernel(const float* __restrict__ A, const float* __restrict__ Bm,
                    const float* __restrict__ bias, float* __restrict__ C,
                    int M, int N, int K, int doRelu)
{
    __shared__ float As[BKK][BM + 4];
    __shared__ float Bs[BKK][BN + 4];
    const int tid = threadIdx.x;
    const int m0 = blockIdx.y * BM;
    const int n0 = blockIdx.x * BN;
    const int tr = tid >> 4;        // 0..15
    const int tc = tid & 15;        // 0..15
    const int lar = tid >> 1;       // 0..127
    const int lac = (tid & 1) * 4;  // 0 or 4

    const float* Aload = A + (size_t)(m0 + lar) * K + lac;
    const float* Bload = Bm + (size_t)(n0 + lar) * K + lac;

    float acc[TM][TN];
    #pragma unroll
    for (int i = 0; i < TM; ++i)
        #pragma unroll
        for (int j = 0; j < TN; ++j) acc[i][j] = 0.f;

    for (int k0 = 0; k0 < K; k0 += BKK) {
        float4 a4 = *(const float4*)(Aload + k0);
        float4 b4 = *(const float4*)(Bload + k0);
        As[lac + 0][lar] = a4.x; As[lac + 1][lar] = a4.y;
        As[lac + 2][lar] = a4.z; As[lac + 3][lar] = a4.w;
        Bs[lac + 0][lar] = b4.x; Bs[lac + 1][lar] = b4.y;
        Bs[lac + 2][lar] = b4.z; Bs[lac + 3][lar] = b4.w;
        __syncthreads();
        #pragma unroll
        for (int kk = 0; kk < BKK; ++kk) {
            float af[TM], bf[TN];
            #pragma unroll
            for (int i = 0; i < TM; ++i) af[i] = As[kk][tr * TM + i];
            #pragma unroll
            for (int j = 0; j < TN; ++j) bf[j] = Bs[kk][tc * TN + j];
            #pragma unroll
            for (int i = 0; i < TM; ++i)
                #pragma unroll
                for (int j = 0; j < TN; ++j)
                    acc[i][j] = fmaf(af[i], bf[j], acc[i][j]);
        }
        __syncthreads();
    }

    float bv[TN];
    #pragma unroll
    for (int j = 0; j < TN; ++j) bv[j] = bias ? bias[n0 + tc * TN + j] : 0.f;
    #pragma unroll
    for (int i = 0; i < TM; ++i) {
        float* crow = C + (size_t)(m0 + tr * TM + i) * N + n0 + tc * TN;
        #pragma unroll
        for (int j = 0; j < TN; ++j) {
            float v = acc[i][j] + bv[j];
            if (doRelu) v = v > 0.f ? v : 0.f;
            crow[j] = v;
        }
    }
}

// ---------------- Selection stage 1: fp32 kth value, window candidates ----------------
#define NB 4096
#define MAXC 2048
#define CAP 32
#define EPSW 4.0e-3f

__global__ __launch_bounds__(256)
void topk_select_kernel(float* __restrict__ F, float* __restrict__ pv, int* __restrict__ pi,
                        int* __restrict__ candIdx, float* __restrict__ candVal,
                        int* __restrict__ candCnt, int* __restrict__ acnt)
{
    __shared__ unsigned hist[NB];
    __shared__ unsigned tsum[256];
    __shared__ float bcv[MAXC];
    __shared__ int   bci[MAXC];
    __shared__ int sb_star, sAcnt, snb, sPair, sCand, sselAll;
    __shared__ float sfk;

    const int b = blockIdx.x;
    const int t = threadIdx.x;
    float* row = F + (size_t)b * HID;

    float v[64];
    #pragma unroll
    for (int i = 0; i < 64; ++i) v[i] = row[t + i * 256];

    #pragma unroll
    for (int i = 0; i < NB / 256; ++i) hist[t + i * 256] = 0;
    if (t == 0) { snb = 0; sPair = 0; sCand = 0; sb_star = -1; sAcnt = 0; sselAll = 0; sfk = 0.f; }
    __syncthreads();

    // histogram of positive values, key = exp + 4 mantissa bits (monotonic)
    #pragma unroll
    for (int i = 0; i < 64; ++i) {
        float val = v[i];
        if (val > 0.f) atomicAdd(&hist[__float_as_uint(val) >> 19], 1u);
    }
    __syncthreads();

    unsigned own = 0;
    #pragma unroll
    for (int j = 0; j < 16; ++j) own += hist[t * 16 + j];
    tsum[t] = own;
    __syncthreads();
    for (int off = 1; off < 256; off <<= 1) {
        unsigned add = (t + off < 256) ? tsum[t + off] : 0u;
        __syncthreads();
        tsum[t] += add;
        __syncthreads();
    }
    const unsigned total = tsum[0];          // count of positives
    const unsigned above_chunk = tsum[t] - own;
    if (t == 0 && total <= (unsigned)KTOP) sselAll = 1;

    if (total > (unsigned)KTOP) {
        unsigned run = above_chunk;
        for (int j = 15; j >= 0; --j) {
            unsigned c = hist[t * 16 + j];
            if (run < KTOP && run + c >= KTOP) { sb_star = t * 16 + j; sAcnt = (int)run; }
            run += c;
        }
    }
    __syncthreads();

    if (sselAll) {
        // <=64 positives: keep all; window machinery unused
        #pragma unroll
        for (int i = 0; i < 64; ++i) {
            float val = v[i];
            if (val > 0.f) {
                int p = atomicAdd(&sPair, 1);
                pv[(size_t)b * KTOP + p] = val;
                pi[(size_t)b * KTOP + p] = t + i * 256;
            }
        }
        __syncthreads();
        int ns = sPair;
        if (t < KTOP && t >= ns) { pv[(size_t)b * KTOP + t] = 0.f; pi[(size_t)b * KTOP + t] = 0; }
        if (t == 0) { acnt[b] = ns; candCnt[b] = 0; }
        return;
    }

    const int bstar = sb_star;
    const int Acnt  = sAcnt;
    const int need  = KTOP - Acnt;

    // collect boundary-bucket members to find the exact fp32 64th value
    #pragma unroll
    for (int i = 0; i < 64; ++i) {
        float val = v[i];
        if (val > 0.f && (int)(__float_as_uint(val) >> 19) == bstar) {
            int p = atomicAdd(&snb, 1);
            if (p < MAXC) { bcv[p] = val; bci[p] = t + i * 256; }
        }
    }
    __syncthreads();
    int nb = snb; if (nb > MAXC) nb = MAXC;

    for (int c = t; c < nb; c += 256) {
        float mv = bcv[c]; int mi = bci[c];
        int r = 0;
        for (int c2 = 0; c2 < nb; ++c2) {
            float ov = bcv[c2];
            if (ov > mv || (ov == mv && bci[c2] < mi)) ++r;
        }
        if (r == need - 1) sfk = mv;   // exactly one candidate has this rank
    }
    __syncthreads();

    const float fk = sfk;
    const float hi = fk + EPSW;
    const float lo = fk - EPSW;

    // classify: > hi definitely in; [lo,hi] ambiguous (refine in fp64); else out
    #pragma unroll
    for (int i = 0; i < 64; ++i) {
        float val = v[i];
        int idx = t + i * 256;
        if (val > hi) {
            int p = atomicAdd(&sPair, 1);
            pv[(size_t)b * KTOP + p] = val;
            pi[(size_t)b * KTOP + p] = idx;
        } else if (val >= lo && val > 0.f) {
            int c = atomicAdd(&sCand, 1);
            if (c < CAP) {
                candIdx[(size_t)b * CAP + c] = idx;
                candVal[(size_t)b * CAP + c] = val;
            }
            row[idx] = 0.f;          // provisionally zero; finalize restores winners
        } else if (val != 0.f) {
            row[idx] = 0.f;
        }
    }
    __syncthreads();
    if (t == 0) {
        acnt[b] = sPair;
        int c = sCand; if (c > CAP) c = CAP;
        candCnt[b] = c;
    }
}

// ---------------- Selection stage 2: fp64 recompute of window candidates ----------------
__global__ __launch_bounds__(256)
void refine_kernel(const float* __restrict__ x, const float* __restrict__ W,
                   const float* __restrict__ be,
                   const int* __restrict__ candIdx, const int* __restrict__ candCnt,
                   double* __restrict__ refined)
{
    const int lane = threadIdx.x & 63;
    const int wave = threadIdx.x >> 6;
    const int task = blockIdx.x * 4 + wave;       // BATCH*CAP tasks
    const int b = task >> 5;                      // /CAP (CAP=32)
    const int slot = task & (CAP - 1);
    if (slot >= candCnt[b]) return;
    const int h = candIdx[(size_t)b * CAP + slot];
    const float* xr = x + (size_t)b * DIN;
    const float* wr = W + (size_t)h * DIN;
    double acc = 0.0;
    #pragma unroll 8
    for (int i = 0; i < DIN / 64; ++i)
        acc += (double)xr[lane + 64 * i] * (double)wr[lane + 64 * i];
    #pragma unroll
    for (int off = 32; off > 0; off >>= 1)
        acc += __shfl_down(acc, off, 64);
    if (lane == 0) refined[(size_t)b * CAP + slot] = acc + (double)be[h];
}

// ---------------- Selection stage 3: rank window by fp64, finalize ----------------
__global__ __launch_bounds__(64)
void finalize_kernel(float* __restrict__ F,
                     const int* __restrict__ candIdx, const float* __restrict__ candVal,
                     const double* __restrict__ refined,
                     const int* __restrict__ candCnt, const int* __restrict__ acnt,
                     float* __restrict__ pv, int* __restrict__ pi)
{
    const int b = blockIdx.x;
    const int t = threadIdx.x;   // 0..63
    const int A = acnt[b];
    const int cnt = candCnt[b];
    int need = KTOP - A; if (need < 0) need = 0;

    if (t >= A) { pv[(size_t)b * KTOP + t] = 0.f; pi[(size_t)b * KTOP + t] = 0; }
    __syncthreads();

    if (t < cnt) {
        double mv = refined[(size_t)b * CAP + t];
        int mi = candIdx[(size_t)b * CAP + t];
        int r = 0;
        for (int c2 = 0; c2 < cnt; ++c2) {
            double ov = refined[(size_t)b * CAP + c2];
            if (ov > mv || (ov == mv && candIdx[(size_t)b * CAP + c2] < mi)) ++r;
        }
        if (r < need) {
            float val = candVal[(size_t)b * CAP + t];
            F[(size_t)b * HID + mi] = val;               // restore winner
            pv[(size_t)b * KTOP + A + r] = val;
            pi[(size_t)b * KTOP + A + r] = mi;
        }
    }
}

// ---------------- Transpose W_dec [DIN,HID] -> Wt [HID,DIN] ----------------
__global__ __launch_bounds__(256)
void transpose_kernel(const float* __restrict__ Wd, float* __restrict__ Wt)
{
    __shared__ float tile[32][33];
    const int tx = threadIdx.x;
    const int ty = threadIdx.y;
    const int h = blockIdx.x * 32 + tx;
    const int d0 = blockIdx.y * 32;
    #pragma unroll
    for (int j = 0; j < 32; j += 8)
        tile[ty + j][tx] = Wd[(size_t)(d0 + ty + j) * HID + h];
    __syncthreads();
    const int d = d0 + tx;
    const int h0 = blockIdx.x * 32;
    #pragma unroll
    for (int j = 0; j < 32; j += 8)
        Wt[(size_t)(h0 + ty + j) * DIN + d] = tile[tx][ty + j];
}

// ---------------- Sparse decode: R[b,:] = sum_j val_j * Wt[idx_j,:] ----------------
__global__ __launch_bounds__(256)
void decode_kernel(const float* __restrict__ pv, const int* __restrict__ pi,
                   const float* __restrict__ Wt, float* __restrict__ R)
{
    __shared__ float sval[KTOP];
    __shared__ int   sidx[KTOP];
    const int b = blockIdx.x;
    const int t = threadIdx.x;
    if (t < KTOP) { sval[t] = pv[(size_t)b * KTOP + t]; sidx[t] = pi[(size_t)b * KTOP + t]; }
    __syncthreads();

    float4 acc[4];
    #pragma unroll
    for (int i = 0; i < 4; ++i) acc[i] = make_float4(0.f, 0.f, 0.f, 0.f);

    for (int j = 0; j < KTOP; ++j) {
        float vv = sval[j];
        if (vv == 0.f) continue;
        const float4* wr = (const float4*)(Wt + (size_t)sidx[j] * DIN);
        #pragma unroll
        for (int i = 0; i < 4; ++i) {
            float4 w = wr[t + i * 256];
            acc[i].x = fmaf(vv, w.x, acc[i].x);
            acc[i].y = fmaf(vv, w.y, acc[i].y);
            acc[i].z = fmaf(vv, w.z, acc[i].z);
            acc[i].w = fmaf(vv, w.w, acc[i].w);
        }
    }
    float4* out = (float4*)(R + (size_t)b * DIN);
    #pragma unroll
    for (int i = 0; i < 4; ++i) out[t + i * 256] = acc[i];
}

// ---------------- fallback exact-fp32 topk (only if ws too small) ----------------
__global__ __launch_bounds__(256)
void topk_fp32_kernel(float* __restrict__ F)
{
    __shared__ unsigned hist[NB];
    __shared__ unsigned tsum[256];
    __shared__ float bcv[MAXC];
    __shared__ int   bci[MAXC];
    __shared__ unsigned char csel[MAXC];
    __shared__ int sb_star, sAcnt, snb, sselAll;

    const int b = blockIdx.x;
    const int t = threadIdx.x;
    float* row = F + (size_t)b * HID;
    float v[64];
    #pragma unroll
    for (int i = 0; i < 64; ++i) v[i] = row[t + i * 256];
    #pragma unroll
    for (int i = 0; i < NB / 256; ++i) hist[t + i * 256] = 0;
    if (t == 0) { snb = 0; sb_star = -1; sAcnt = 0; sselAll = 0; }
    __syncthreads();
    #pragma unroll
    for (int i = 0; i < 64; ++i)
        if (v[i] > 0.f) atomicAdd(&hist[__float_as_uint(v[i]) >> 19], 1u);
    __syncthreads();
    unsigned own = 0;
    #pragma unroll
    for (int j = 0; j < 16; ++j) own += hist[t * 16 + j];
    tsum[t] = own;
    __syncthreads();
    for (int off = 1; off < 256; off <<= 1) {
        unsigned add = (t + off < 256) ? tsum[t + off] : 0u;
        __syncthreads();
        tsum[t] += add;
        __syncthreads();
    }
    const unsigned total = tsum[0];
    const unsigned above_chunk = tsum[t] - own;
    if (t == 0 && total <= (unsigned)KTOP) sselAll = 1;
    if (total > (unsigned)KTOP) {
        unsigned run = above_chunk;
        for (int j = 15; j >= 0; --j) {
            unsigned c = hist[t * 16 + j];
            if (run < KTOP && run + c >= KTOP) { sb_star = t * 16 + j; sAcnt = (int)run; }
            run += c;
        }
    }
    __syncthreads();
    if (sselAll) return;
    const int bstar = sb_star;
    const int need = KTOP - sAcnt;
    #pragma unroll
    for (int i = 0; i < 64; ++i) {
        float val = v[i];
        if (val > 0.f && (int)(__float_as_uint(val) >> 19) == bstar) {
            int p = atomicAdd(&snb, 1);
            if (p < MAXC) { bcv[p] = val; bci[p] = t + i * 256; }
        }
    }
    __syncthreads();
    int nb = snb; if (nb > MAXC) nb = MAXC;
    for (int c = t; c < nb; c += 256) {
        float mv = bcv[c]; int mi = bci[c];
        int r = 0;
        for (int c2 = 0; c2 < nb; ++c2) {
            float ov = bcv[c2];
            if (ov > mv || (ov == mv && bci[c2] < mi)) ++r;
        }
        csel[c] = (r < need) ? 1 : 0;
    }
    __syncthreads();
    #pragma unroll
    for (int i = 0; i < 64; ++i) {
        float val = v[i];
        int idx = t + i * 256;
        bool keep = false;
        if (val > 0.f) {
            int key = (int)(__float_as_uint(val) >> 19);
            if (key > bstar) keep = true;
            else if (key == bstar)
                for (int c2 = 0; c2 < nb; ++c2)
                    if (bci[c2] == idx) { keep = (csel[c2] != 0); break; }
        }
        if (!keep && val != 0.f) row[idx] = 0.f;
    }
}

extern "C" void kernel_launch(void* const* d_in, const int* in_sizes, int n_in,
                              void* d_out, int out_size, void* d_ws, size_t ws_size,
                              hipStream_t stream)
{
    const float* x     = (const float*)d_in[0];
    const float* W_enc = (const float*)d_in[1];
    const float* b_enc = (const float*)d_in[2];
    const float* W_dec = (const float*)d_in[3];

    float* sparse = (float*)d_out;                      // [BATCH, HID]
    float* recon  = sparse + (size_t)BATCH * HID;       // [BATCH, DIN]

    // workspace layout
    char* p = (char*)d_ws;
    size_t off = 0;
    float* pv      = (float*)(p + off); off += (size_t)BATCH * KTOP * 4;   // 2 MB
    int*   pi      = (int*)  (p + off); off += (size_t)BATCH * KTOP * 4;   // 2 MB
    int*   candIdx = (int*)  (p + off); off += (size_t)BATCH * CAP * 4;    // 1 MB
    float* candVal = (float*)(p + off); off += (size_t)BATCH * CAP * 4;    // 1 MB
    double* refined= (double*)(p + off); off += (size_t)BATCH * CAP * 8;   // 2 MB
    int*   candCnt = (int*)  (p + off); off += (size_t)BATCH * 4;          // 32 KB
    int*   acnt    = (int*)  (p + off); off += (size_t)BATCH * 4;          // 32 KB
    const size_t selBytes = off;
    float* Wt      = (float*)(p + off); off += (size_t)HID * DIN * 4;      // 256 MB
    const int haveSel = (ws_size >= selBytes) ? 1 : 0;
    const int haveWt  = (ws_size >= off) ? 1 : 0;

    // 1) dense encoder features (fp32 values)
    gemm_nt_kernel<<<dim3(HID / BN, BATCH / BM), 256, 0, stream>>>(
        x, W_enc, b_enc, sparse, BATCH, HID, DIN, 1);

    if (haveSel) {
        // 2) fp32 kth + boundary window
        topk_select_kernel<<<BATCH, 256, 0, stream>>>(sparse, pv, pi, candIdx, candVal,
                                                      candCnt, acnt);
        // 3) fp64 recompute of window candidates (~1.6 per row expected)
        refine_kernel<<<BATCH * CAP / 4, 256, 0, stream>>>(x, W_enc, b_enc,
                                                           candIdx, candCnt, refined);
        // 4) final ranking by fp64, restore winners, finish pair list
        finalize_kernel<<<BATCH, 64, 0, stream>>>(sparse, candIdx, candVal, refined,
                                                  candCnt, acnt, pv, pi);
        // 5) decode
        if (haveWt) {
            transpose_kernel<<<dim3(HID / 32, DIN / 32), dim3(32, 8), 0, stream>>>(W_dec, Wt);
            decode_kernel<<<BATCH, 256, 0, stream>>>(pv, pi, Wt, recon);
        } else {
            gemm_nt_kernel<<<dim3(DIN / BN, BATCH / BM), 256, 0, stream>>>(
                sparse, W_dec, nullptr, recon, BATCH, DIN, HID, 0);
        }
    } else {
        topk_fp32_kernel<<<BATCH, 256, 0, stream>>>(sparse);
        gemm_nt_kernel<<<dim3(DIN / BN, BATCH / BM), 256, 0, stream>>>(
            sparse, W_dec, nullptr, recon, BATCH, DIN, HID, 0);
    }
}